// Round 14
// baseline (96.138 us; speedup 1.0000x reference)
//
#include <hip/hip_runtime.h>

#define CC 64
#define TT 8192
#define NB 8
#define NW32 16384          // 32-t windows: 64 b * 256
#define GRID 768            // 3 blocks/CU (VGPR-limited 3 waves/SIMD)
#define NWAVES (GRID * 4)   // 3072 waves; ~5.3 windows each

typedef __attribute__((ext_vector_type(8))) short bf16x8;
typedef __attribute__((ext_vector_type(16))) float f32x16;
typedef __attribute__((ext_vector_type(4))) int i32x4;

union I4B8 { i32x4 i; bf16x8 b; };

__device__ __forceinline__ unsigned short f32_to_bf16_rn(float f) {
    unsigned u = __float_as_uint(f);
    unsigned r = (u + 0x7FFFu + ((u >> 16) & 1u)) >> 16;
    return (unsigned short)r;
}
__device__ __forceinline__ float bf16_to_f32(unsigned short h) {
    return __uint_as_float(((unsigned)h) << 16);
}

// ---- main: persistent; W hi/lo 32x32-MFMA fragments in LDS (16 KB);
//      wave = 32-t window, all 64 rows via 2 M-tiles; zero steady barriers. --
// W frag layout (bytes): (((mt*4+ks)*2+h)*64 + lane)*16 + j*2
//   A-frag (32x32x16): lane holds W[p = mt*32 + (lane&31)][c = ks*16 + (lane>>5)*8 + j]
__global__ __launch_bounds__(256, 3) void rpg_main(
    const float* __restrict__ x,
    const float* __restrict__ sigma,
    const float* __restrict__ rho,
    const float* __restrict__ E,
    const float* __restrict__ F,
    float* __restrict__ out)
{
    __shared__ __align__(16) char wsl[16384];

    const int tid  = threadIdx.x;
    const int w    = tid >> 6;
    const int lane = tid & 63;
    const int l31  = lane & 31;      // t within window; MFMA A-row/B-col/D-col
    const int hi   = lane >> 5;      // k-group (A/B); row-half selector (D)

    // ---- build W fragments in LDS, once per block ---------------------------
    // thread tid <-> (r = tid>>6, c = tid&63); E/F [r][c][0..8) contiguous loads
    {
        const int r = tid >> 6;
        const int c = tid & 63;
        const float g = (8.0f / (1e-5f + fabsf(sigma[r]))) *
                        (8.0f / (1e-5f + fabsf(rho[r]))) * 0.25f;
        const int ks = c >> 4, h5 = (c >> 3) & 1, j = c & 7;
        const float4 e0 = *(const float4*)(E + (r * 64 + c) * 8);
        const float4 e1 = *(const float4*)(E + (r * 64 + c) * 8 + 4);
        const float4 fq0 = *(const float4*)(F + (r * 64 + c) * 8);
        const float4 fq1 = *(const float4*)(F + (r * 64 + c) * 8 + 4);
        const float ev[8] = {e0.x, e0.y, e0.z, e0.w, e1.x, e1.y, e1.z, e1.w};
        const float fv[8] = {fq0.x, fq0.y, fq0.z, fq0.w, fq1.x, fq1.y, fq1.z, fq1.w};
        #pragma unroll
        for (int n = 0; n < 8; ++n) {
            const int pb = r * 8 + n;            // 0..31
            {   // E side: p = pb, mt = 0, scaled
                const float val = ev[n] * g;
                const unsigned short hv = f32_to_bf16_rn(val);
                const unsigned short lv = f32_to_bf16_rn(val - bf16_to_f32(hv));
                char* base = wsl + ((((0 * 4 + ks) * 2 + 0) * 64 + (h5 << 5) + pb) << 4) + j * 2;
                *(unsigned short*)base = hv;
                *(unsigned short*)(base + 1024) = lv;
            }
            {   // F side: p = 32 + pb, mt = 1, unscaled
                const float val = fv[n];
                const unsigned short hv = f32_to_bf16_rn(val);
                const unsigned short lv = f32_to_bf16_rn(val - bf16_to_f32(hv));
                char* base = wsl + ((((1 * 4 + ks) * 2 + 0) * 64 + (h5 << 5) + pb) << 4) + j * 2;
                *(unsigned short*)base = hv;
                *(unsigned short*)(base + 1024) = lv;
            }
        }
    }

    int wid = blockIdx.x * 4 + w;

    // ---- prefetch window 0: B-frag order, 2x128B full-line segments/instr ---
    float f[32];
    {
        const int b = wid >> 8, t0 = (wid & 255) << 5;
        const float* xp = x + b * (CC * TT) + t0 + l31;
        #pragma unroll
        for (int k = 0; k < 32; ++k) {
            const int c = (k >> 3) * 16 + hi * 8 + (k & 7);
            f[k] = xp[c * TT];
        }
    }

    __syncthreads();   // W build complete (the only barrier)

    #pragma unroll 1
    while (wid < NW32) {
        // ---- convert f -> bf16 hi/lo B-frags (in registers) -----------------
        bf16x8 xh[4], xl[4];
        #pragma unroll
        for (int ks = 0; ks < 4; ++ks) {
            unsigned hw[4], lw[4];
            #pragma unroll
            for (int k = 0; k < 4; ++k) {
                const float f0 = f[ks * 8 + 2 * k];
                const float f1 = f[ks * 8 + 2 * k + 1];
                const unsigned u0 = __float_as_uint(f0), u1 = __float_as_uint(f1);
                hw[k] = (u0 >> 16) | (u1 & 0xFFFF0000u);
                const float h0 = __uint_as_float(u0 & 0xFFFF0000u);
                const float h1 = __uint_as_float(u1 & 0xFFFF0000u);
                lw[k] = (__float_as_uint(f0 - h0) >> 16) |
                        (__float_as_uint(f1 - h1) & 0xFFFF0000u);
            }
            I4B8 H, L;
            H.i = (i32x4){(int)hw[0], (int)hw[1], (int)hw[2], (int)hw[3]};
            L.i = (i32x4){(int)lw[0], (int)lw[1], (int)lw[2], (int)lw[3]};
            xh[ks] = H.b;
            xl[ks] = L.b;
        }

        const int b  = wid >> 8;
        const int t0 = (wid & 255) << 5;
        const int nxt = wid + NWAVES;

        // ---- prefetch next window (flies under MFMA + epilogue + stores) ----
        if (nxt < NW32) {
            const int nb = nxt >> 8, nt0 = (nxt & 255) << 5;
            const float* xp = x + nb * (CC * TT) + nt0 + l31;
            #pragma unroll
            for (int k = 0; k < 32; ++k) {
                const int c = (k >> 3) * 16 + hi * 8 + (k & 7);
                f[k] = xp[c * TT];
            }
        }

        // ---- GEMM: acc[mt] = Y rows [mt*32, mt*32+32) x 32 t, 3-pass hi/lo --
        f32x16 acc0 = {}, acc1 = {};
        #pragma unroll
        for (int ks = 0; ks < 4; ++ks) {
            const int fb0 = ((0 * 4 + ks) * 2) * 1024 + lane * 16;
            const bf16x8 wh0 = ((const I4B8*)(wsl + fb0))->b;
            const bf16x8 wl0 = ((const I4B8*)(wsl + fb0 + 1024))->b;
            acc0 = __builtin_amdgcn_mfma_f32_32x32x16_bf16(wh0, xh[ks], acc0, 0, 0, 0);
            acc0 = __builtin_amdgcn_mfma_f32_32x32x16_bf16(wh0, xl[ks], acc0, 0, 0, 0);
            acc0 = __builtin_amdgcn_mfma_f32_32x32x16_bf16(wl0, xh[ks], acc0, 0, 0, 0);
        }
        #pragma unroll
        for (int ks = 0; ks < 4; ++ks) {
            const int fb1 = ((1 * 4 + ks) * 2) * 1024 + lane * 16;
            const bf16x8 wh1 = ((const I4B8*)(wsl + fb1))->b;
            const bf16x8 wl1 = ((const I4B8*)(wsl + fb1 + 1024))->b;
            acc1 = __builtin_amdgcn_mfma_f32_32x32x16_bf16(wh1, xh[ks], acc1, 0, 0, 0);
            acc1 = __builtin_amdgcn_mfma_f32_32x32x16_bf16(wh1, xl[ks], acc1, 0, 0, 0);
            acc1 = __builtin_amdgcn_mfma_f32_32x32x16_bf16(wl1, xh[ks], acc1, 0, 0, 0);
        }

        // ---- epilogue: D row = (reg&3) + 8*(reg>>2) + 4*hi, col = l31 -------
        // acc0 reg (rank*4+ni): xe[rank][n = ni+4hi] ; acc1: xf[rank][m = mi+4hi]
        // partner (lane^32) acc1 holds the other m-half.
        float xfo[16];
        #pragma unroll
        for (int i = 0; i < 16; ++i) xfo[i] = __shfl_xor(acc1[i], 32);

        float zo[16], zp[16];
        float pm = 0.0f;
        #pragma unroll
        for (int ni = 0; ni < 4; ++ni) {
            #pragma unroll
            for (int mi = 0; mi < 4; ++mi) {
                float a = acc0[0 + ni] * acc1[0 + mi];
                a = fmaf(acc0[4 + ni],  acc1[4 + mi],  a);
                a = fmaf(acc0[8 + ni],  acc1[8 + mi],  a);
                a = fmaf(acc0[12 + ni], acc1[12 + mi], a);
                float s = __builtin_amdgcn_sqrtf(fabsf(a) + 0.01f) - 0.1f;
                float v = copysignf(s, a);
                zo[ni * 4 + mi] = v;
                pm = fmaxf(pm, fabsf(v));

                float a2 = acc0[0 + ni] * xfo[0 + mi];
                a2 = fmaf(acc0[4 + ni],  xfo[4 + mi],  a2);
                a2 = fmaf(acc0[8 + ni],  xfo[8 + mi],  a2);
                a2 = fmaf(acc0[12 + ni], xfo[12 + mi], a2);
                float s2 = __builtin_amdgcn_sqrtf(fabsf(a2) + 0.01f) - 0.1f;
                float v2 = copysignf(s2, a2);
                zp[ni * 4 + mi] = v2;
                pm = fmaxf(pm, fabsf(v2));
            }
        }

        pm = fmaxf(pm, __shfl_xor(pm, 32));
        const float rinv = __builtin_amdgcn_rcpf(pm + 1e-5f);

        // own half: p = ni*8+mi + 36*hi ; partner half: p = ni*8+mi + 28*hi+4
        float* ob  = out + b * (64 * TT) + t0 + l31;
        float* ob1 = ob + (36 * hi) * TT;
        float* ob2 = ob + (28 * hi + 4) * TT;
        #pragma unroll
        for (int ni = 0; ni < 4; ++ni) {
            #pragma unroll
            for (int mi = 0; mi < 4; ++mi) {
                ob1[(ni * 8 + mi) * TT] = zo[ni * 4 + mi] * rinv;
                ob2[(ni * 8 + mi) * TT] = zp[ni * 4 + mi] * rinv;
            }
        }

        wid = nxt;
    }
}

extern "C" void kernel_launch(void* const* d_in, const int* in_sizes, int n_in,
                              void* d_out, int out_size, void* d_ws, size_t ws_size,
                              hipStream_t stream) {
    const float* x     = (const float*)d_in[0];
    const float* sigma = (const float*)d_in[1];
    const float* rho   = (const float*)d_in[2];
    const float* E     = (const float*)d_in[3];
    const float* F     = (const float*)d_in[4];
    float* out = (float*)d_out;

    rpg_main<<<GRID, 256, 0, stream>>>(x, sigma, rho, E, F, out);
}